// Round 1
// baseline (3794.801 us; speedup 1.0000x reference)
//
#include <hip/hip_runtime.h>

#define B 8
#define C 256
#define H 56
#define W 56
#define HW (H*W)          // 3136
#define CHW (C*HW)        // 802816
#define NOFF 18
#define EPS 1e-5f

// ---------------------------------------------------------------------------
// K1: out = relu(bn1(conv3x3(x, w1)))  -> t1
// block = 448 threads = 8 rows x 56 cols; 16 output channels per block
// grid = (Co/16=16, H/8=7, B=8)
// ---------------------------------------------------------------------------
__global__ __launch_bounds__(448) void conv1_bn_relu(
    const float* __restrict__ x, const float* __restrict__ w1,
    const float* __restrict__ g, const float* __restrict__ bb,
    const float* __restrict__ m, const float* __restrict__ v,
    float* __restrict__ t1)
{
  __shared__ float tile[10*58];
  const int co0 = blockIdx.x * 16;
  const int r0  = blockIdx.y * 8;
  const int b   = blockIdx.z;
  const int tid = threadIdx.x;
  const int lr  = tid / 56;    // 0..7
  const int cc  = tid % 56;    // 0..55

  float acc[16];
  #pragma unroll
  for (int i = 0; i < 16; ++i) acc[i] = 0.f;

  const float* xb = x + (size_t)b*CHW;

  for (int ci = 0; ci < C; ++ci) {
    __syncthreads();
    // stage rows r0-1..r0+8, cols -1..56 of plane ci (zero-padded)
    const float* xp = xb + ci*HW;
    for (int li = tid; li < 580; li += 448) {
      int ty = li / 58, tx = li % 58;
      int gy = r0 - 1 + ty, gx = tx - 1;
      float val = 0.f;
      if (gy >= 0 && gy < H && gx >= 0 && gx < W) val = xp[gy*W + gx];
      tile[ty*58 + tx] = val;
    }
    __syncthreads();

    float xv[9];
    #pragma unroll
    for (int dy = 0; dy < 3; ++dy)
      #pragma unroll
      for (int dx = 0; dx < 3; ++dx)
        xv[dy*3+dx] = tile[(lr+dy)*58 + (cc+dx)];

    const float* wp = w1 + (size_t)co0*2304 + ci*9;
    #pragma unroll
    for (int co = 0; co < 16; ++co) {
      const float* wq = wp + co*2304;   // uniform -> scalar loads
      float s = acc[co];
      #pragma unroll
      for (int t = 0; t < 9; ++t) s += xv[t]*wq[t];
      acc[co] = s;
    }
  }

  const int orow = r0 + lr;
  #pragma unroll
  for (int co = 0; co < 16; ++co) {
    int c = co0 + co;
    float inv  = g[c] * rsqrtf(v[c] + EPS);
    float beta = bb[c] - m[c]*inv;
    float val  = acc[co]*inv + beta;
    t1[(size_t)b*CHW + c*HW + orow*W + cc] = val > 0.f ? val : 0.f;
  }
}

// ---------------------------------------------------------------------------
// K2: offset = conv3x3(t1, off_w) + off_b   (offset_bias(dil=1) == 0)
// one thread per output pixel, 18 channel accumulators
// ---------------------------------------------------------------------------
__global__ __launch_bounds__(256) void offset_conv(
    const float* __restrict__ t1, const float* __restrict__ ow,
    const float* __restrict__ ob, float* __restrict__ toff)
{
  int p = blockIdx.x*256 + threadIdx.x;
  if (p >= B*HW) return;
  int b = p / HW, rem = p % HW;
  int ho = rem / W, wo = rem % W;

  float acc[18];
  #pragma unroll
  for (int i = 0; i < 18; ++i) acc[i] = 0.f;

  const float* tb = t1 + (size_t)b*CHW;
  for (int ci = 0; ci < C; ++ci) {
    const float* pl = tb + ci*HW;
    #pragma unroll
    for (int ky = 0; ky < 3; ++ky) {
      int y = ho - 1 + ky;
      #pragma unroll
      for (int kx = 0; kx < 3; ++kx) {
        int xx = wo - 1 + kx;
        float val = (y >= 0 && y < H && xx >= 0 && xx < W) ? pl[y*W + xx] : 0.f;
        const float* wq = ow + ci*9 + ky*3 + kx;   // + c*2304, uniform
        #pragma unroll
        for (int c = 0; c < 18; ++c)
          acc[c] += val * wq[c*2304];
      }
    }
  }
  #pragma unroll
  for (int c = 0; c < 18; ++c)
    toff[(size_t)b*(NOFF*HW) + c*HW + rem] = acc[c] + ob[c];
}

// ---------------------------------------------------------------------------
// K3: out = relu(bn2(deform_conv(t1, w2, toff)) + x)
// block = 448 threads = 8 rows x 56 cols; 16 output channels per block
// grid = (16, 7, 8)
// ---------------------------------------------------------------------------
__global__ __launch_bounds__(448) void deform_bn_add_relu(
    const float* __restrict__ t1, const float* __restrict__ w2,
    const float* __restrict__ toff, const float* __restrict__ x,
    const float* __restrict__ g, const float* __restrict__ bb,
    const float* __restrict__ m, const float* __restrict__ v,
    float* __restrict__ out)
{
  const int co0 = blockIdx.x * 16;
  const int r0  = blockIdx.y * 8;
  const int b   = blockIdx.z;
  const int tid = threadIdx.x;
  const int ho  = r0 + tid / 56;
  const int wo  = tid % 56;

  float acc[16];
  #pragma unroll
  for (int i = 0; i < 16; ++i) acc[i] = 0.f;

  const float* tb   = t1 + (size_t)b*CHW;
  const float* offb = toff + (size_t)b*(NOFF*HW) + ho*W + wo;

  for (int k = 0; k < 9; ++k) {
    const int ky = k/3, kx = k%3;
    float offy = offb[k*HW];
    float offx = offb[(9+k)*HW];
    float yf = (float)(ho - 1 + ky) + offy;
    float xf = (float)(wo - 1 + kx) + offx;
    float y0f = floorf(yf), x0f = floorf(xf);
    float ty = yf - y0f,   tx = xf - x0f;
    int y0 = (int)y0f, x0 = (int)x0f;
    int y1 = y0 + 1,   x1 = x0 + 1;
    bool vy0 = (y0 >= 0) & (y0 < H);
    bool vy1 = (y1 >= 0) & (y1 < H);
    bool vx0 = (x0 >= 0) & (x0 < W);
    bool vx1 = (x1 >= 0) & (x1 < W);
    int cy0 = min(max(y0,0),H-1), cy1 = min(max(y1,0),H-1);
    int cx0 = min(max(x0,0),W-1), cx1 = min(max(x1,0),W-1);
    float wy0 = 1.f - ty, wx0 = 1.f - tx;
    float w00 = (vy0 & vx0) ? wy0*wx0 : 0.f;
    float w01 = (vy0 & vx1) ? wy0*tx  : 0.f;
    float w10 = (vy1 & vx0) ? ty*wx0  : 0.f;
    float w11 = (vy1 & vx1) ? ty*tx   : 0.f;
    int i00 = cy0*W + cx0, i01 = cy0*W + cx1;
    int i10 = cy1*W + cx0, i11 = cy1*W + cx1;

    for (int ci = 0; ci < C; ++ci) {
      const float* pl = tb + ci*HW;
      float val = w00*pl[i00] + w01*pl[i01] + w10*pl[i10] + w11*pl[i11];
      const float* wq = w2 + (size_t)co0*2304 + ci*9 + k;   // uniform
      #pragma unroll
      for (int co = 0; co < 16; ++co)
        acc[co] += val * wq[co*2304];
    }
  }

  const size_t oidx = (size_t)b*CHW + ho*W + wo;   // + c*HW per channel
  #pragma unroll
  for (int co = 0; co < 16; ++co) {
    int c = co0 + co;
    float inv  = g[c] * rsqrtf(v[c] + EPS);
    float beta = bb[c] - m[c]*inv;
    float val  = acc[co]*inv + beta + x[oidx + c*HW];
    out[oidx + c*HW] = val > 0.f ? val : 0.f;
  }
}

extern "C" void kernel_launch(void* const* d_in, const int* in_sizes, int n_in,
                              void* d_out, int out_size, void* d_ws, size_t ws_size,
                              hipStream_t stream) {
  const float* x   = (const float*)d_in[0];
  const float* w1  = (const float*)d_in[1];
  const float* g1  = (const float*)d_in[2];
  const float* b1  = (const float*)d_in[3];
  const float* m1  = (const float*)d_in[4];
  const float* v1  = (const float*)d_in[5];
  const float* ow  = (const float*)d_in[6];
  const float* ob  = (const float*)d_in[7];
  const float* w2  = (const float*)d_in[8];
  const float* g2  = (const float*)d_in[9];
  const float* b2  = (const float*)d_in[10];
  const float* m2  = (const float*)d_in[11];
  const float* v2  = (const float*)d_in[12];
  float* out  = (float*)d_out;
  float* t1   = (float*)d_ws;                    // B*C*H*W fp32 = 25.7 MB
  float* toff = t1 + (size_t)B*CHW;              // B*18*H*W fp32 = 1.8 MB

  dim3 grid1(16, 7, 8);
  conv1_bn_relu<<<grid1, 448, 0, stream>>>(x, w1, g1, b1, m1, v1, t1);
  offset_conv<<<(B*HW + 255)/256, 256, 0, stream>>>(t1, ow, ob, toff);
  deform_bn_add_relu<<<grid1, 448, 0, stream>>>(t1, w2, toff, x, g2, b2, m2, v2, out);
}

// Round 2
// 2853.065 us; speedup vs baseline: 1.3301x; 1.3301x over previous
//
#include <hip/hip_runtime.h>

#define B 8
#define C 256
#define H 56
#define W 56
#define HW (H*W)          // 3136
#define CHW (C*HW)        // 802816
#define NOFF 18
#define EPS 1e-5f

// ---------------------------------------------------------------------------
// P0: transpose w2 [co][ci][k] -> w2t [k][ci][co]  (589824 elems)
// ---------------------------------------------------------------------------
__global__ __launch_bounds__(256) void prep_w2t(
    const float* __restrict__ w2, float* __restrict__ w2t)
{
  int idx = blockIdx.x*256 + threadIdx.x;   // (k*256+ci)*256+co
  if (idx >= 9*256*256) return;
  int co = idx & 255;
  int r  = idx >> 8;
  int ci = r & 255;
  int k  = r >> 8;
  w2t[idx] = w2[co*2304 + ci*9 + k];
}

// ---------------------------------------------------------------------------
// K1: t1 = relu(bn1(conv3x3(x, w1)))  written NHWC: t1[((b*H+y)*W+x)*256+c]
// block = 448 threads = 8 rows x 56 cols; 16 output channels per block
// grid = (16, 7, 8); stages 4 ci planes per sync round
// ---------------------------------------------------------------------------
__global__ __launch_bounds__(448) void conv1_bn_relu(
    const float* __restrict__ x, const float* __restrict__ w1,
    const float* __restrict__ g, const float* __restrict__ bb,
    const float* __restrict__ m, const float* __restrict__ v,
    float* __restrict__ t1)
{
  __shared__ float tile[4][580];   // 4 ci planes of 10x58
  const int co0 = blockIdx.x * 16;
  const int r0  = blockIdx.y * 8;
  const int b   = blockIdx.z;
  const int tid = threadIdx.x;
  const int lr  = tid / 56;
  const int cc  = tid % 56;

  float acc[16];
  #pragma unroll
  for (int i = 0; i < 16; ++i) acc[i] = 0.f;

  const float* xb = x + (size_t)b*CHW;

  for (int ci0 = 0; ci0 < C; ci0 += 4) {
    __syncthreads();
    for (int li = tid; li < 4*580; li += 448) {
      int pl = li / 580, rem = li % 580;
      int ty = rem / 58, tx = rem % 58;
      int gy = r0 - 1 + ty, gx = tx - 1;
      float val = 0.f;
      if (gy >= 0 && gy < H && gx >= 0 && gx < W)
        val = xb[(ci0+pl)*HW + gy*W + gx];
      tile[pl][ty*58 + tx] = val;
    }
    __syncthreads();

    #pragma unroll
    for (int pl = 0; pl < 4; ++pl) {
      const int ci = ci0 + pl;
      float xv[9];
      #pragma unroll
      for (int dy = 0; dy < 3; ++dy)
        #pragma unroll
        for (int dx = 0; dx < 3; ++dx)
          xv[dy*3+dx] = tile[pl][(lr+dy)*58 + (cc+dx)];

      #pragma unroll
      for (int co = 0; co < 16; ++co) {
        const float* wq = w1 + (size_t)(co0+co)*2304 + ci*9;  // uniform -> s_load
        float s = acc[co];
        #pragma unroll
        for (int t = 0; t < 9; ++t) s += xv[t]*wq[t];
        acc[co] = s;
      }
    }
  }

  const int orow = r0 + lr;
  float o[16];
  #pragma unroll
  for (int co = 0; co < 16; ++co) {
    int c = co0 + co;
    float inv  = g[c] * rsqrtf(v[c] + EPS);
    float beta = bb[c] - m[c]*inv;
    float val  = acc[co]*inv + beta;
    o[co] = val > 0.f ? val : 0.f;
  }
  float* tb = t1 + ((size_t)(b*H + orow)*W + cc)*256 + co0;
  #pragma unroll
  for (int co = 0; co < 16; co += 4) {
    float4 v4 = make_float4(o[co], o[co+1], o[co+2], o[co+3]);
    *(float4*)(tb + co) = v4;
  }
}

// ---------------------------------------------------------------------------
// K2: toff += conv3x3(t1, off_w) (+ off_b on chunk 0); toff pre-zeroed.
// thread per pixel; grid.y = 8 ci-chunks of 32; NHWC float4 loads.
// ---------------------------------------------------------------------------
__global__ __launch_bounds__(256) void offset_conv(
    const float* __restrict__ t1, const float* __restrict__ ow,
    const float* __restrict__ ob, float* __restrict__ toff)
{
  const int p = blockIdx.x*256 + threadIdx.x;    // 98*256 = 25088 exact
  const int cichunk = blockIdx.y * 32;
  const int b  = p / HW, rem = p % HW;
  const int ho = rem / W, wo = rem % W;

  float acc[18];
  if (blockIdx.y == 0) {
    #pragma unroll
    for (int c = 0; c < 18; ++c) acc[c] = ob[c];
  } else {
    #pragma unroll
    for (int c = 0; c < 18; ++c) acc[c] = 0.f;
  }

  #pragma unroll
  for (int ky = 0; ky < 3; ++ky) {
    int y = ho - 1 + ky;
    if (y < 0 || y >= H) continue;
    #pragma unroll
    for (int kx = 0; kx < 3; ++kx) {
      int xx = wo - 1 + kx;
      if (xx < 0 || xx >= W) continue;
      const int k = ky*3 + kx;
      const float* base = t1 + ((size_t)(b*H + y)*W + xx)*256 + cichunk;
      for (int q = 0; q < 8; ++q) {
        float4 v4 = *(const float4*)(base + q*4);
        const int ci = cichunk + q*4;
        #pragma unroll
        for (int c = 0; c < 18; ++c) {
          const float* wr = ow + ((size_t)c*256 + ci)*9 + k;   // uniform -> s_load
          acc[c] += v4.x*wr[0] + v4.y*wr[9] + v4.z*wr[18] + v4.w*wr[27];
        }
      }
    }
  }

  float* od = toff + (size_t)b*(NOFF*HW) + rem;
  #pragma unroll
  for (int c = 0; c < 18; ++c)
    atomicAdd(od + c*HW, acc[c]);
}

// ---------------------------------------------------------------------------
// K3: out = relu(bn2(deform_conv(t1, w2, toff)) + x)
// block = 448 = 8 rows x 56 cols; 32 output channels; grid (8, 7, 8)
// NHWC t1: per (k, ci-quad): 4 float4 corner loads shared across 32 co
// ---------------------------------------------------------------------------
__global__ __launch_bounds__(448) void deform_bn_add_relu(
    const float* __restrict__ t1, const float* __restrict__ w2t,
    const float* __restrict__ toff, const float* __restrict__ x,
    const float* __restrict__ g, const float* __restrict__ bb,
    const float* __restrict__ m, const float* __restrict__ v,
    float* __restrict__ out)
{
  const int co0 = blockIdx.x * 32;
  const int r0  = blockIdx.y * 8;
  const int b   = blockIdx.z;
  const int tid = threadIdx.x;
  const int ho  = r0 + tid / 56;
  const int wo  = tid % 56;

  float acc[32];
  #pragma unroll
  for (int i = 0; i < 32; ++i) acc[i] = 0.f;

  const float* tb   = t1 + (size_t)(b*H)*W*256;
  const float* offb = toff + (size_t)b*(NOFF*HW) + ho*W + wo;

  for (int k = 0; k < 9; ++k) {
    const int ky = k/3, kx = k%3;
    float offy = offb[k*HW];
    float offx = offb[(9+k)*HW];
    float yf = (float)(ho - 1 + ky) + offy;
    float xf = (float)(wo - 1 + kx) + offx;
    float y0f = floorf(yf), x0f = floorf(xf);
    float ty = yf - y0f,   tx = xf - x0f;
    int y0 = (int)y0f, x0 = (int)x0f;
    int y1 = y0 + 1,   x1 = x0 + 1;
    bool vy0 = (y0 >= 0) & (y0 < H);
    bool vy1 = (y1 >= 0) & (y1 < H);
    bool vx0 = (x0 >= 0) & (x0 < W);
    bool vx1 = (x1 >= 0) & (x1 < W);
    int cy0 = min(max(y0,0),H-1), cy1 = min(max(y1,0),H-1);
    int cx0 = min(max(x0,0),W-1), cx1 = min(max(x1,0),W-1);
    float wy0 = 1.f - ty, wx0 = 1.f - tx;
    float w00 = (vy0 & vx0) ? wy0*wx0 : 0.f;
    float w01 = (vy0 & vx1) ? wy0*tx  : 0.f;
    float w10 = (vy1 & vx0) ? ty*wx0  : 0.f;
    float w11 = (vy1 & vx1) ? ty*tx   : 0.f;
    const float* b00 = tb + (size_t)(cy0*W + cx0)*256;
    const float* b01 = tb + (size_t)(cy0*W + cx1)*256;
    const float* b10 = tb + (size_t)(cy1*W + cx0)*256;
    const float* b11 = tb + (size_t)(cy1*W + cx1)*256;

    for (int q = 0; q < 64; ++q) {
      float4 c00 = *(const float4*)(b00 + q*4);
      float4 c01 = *(const float4*)(b01 + q*4);
      float4 c10 = *(const float4*)(b10 + q*4);
      float4 c11 = *(const float4*)(b11 + q*4);
      float4 val;
      val.x = w00*c00.x + w01*c01.x + w10*c10.x + w11*c11.x;
      val.y = w00*c00.y + w01*c01.y + w10*c10.y + w11*c11.y;
      val.z = w00*c00.z + w01*c01.z + w10*c10.z + w11*c11.z;
      val.w = w00*c00.w + w01*c01.w + w10*c10.w + w11*c11.w;
      // w2t rows for ci = 4q..4q+3, co consecutive -> batched s_load
      const float* wrow = w2t + ((size_t)(k*256 + q*4))*256 + co0;
      #pragma unroll
      for (int co = 0; co < 32; ++co) {
        acc[co] += val.x*wrow[co] + val.y*wrow[256+co]
                 + val.z*wrow[512+co] + val.w*wrow[768+co];
      }
    }
  }

  const size_t oidx = (size_t)b*CHW + ho*W + wo;   // + c*HW per channel
  #pragma unroll
  for (int co = 0; co < 32; ++co) {
    int c = co0 + co;
    float inv  = g[c] * rsqrtf(v[c] + EPS);
    float beta = bb[c] - m[c]*inv;
    float val  = acc[co]*inv + beta + x[oidx + (size_t)c*HW];
    out[oidx + (size_t)c*HW] = val > 0.f ? val : 0.f;
  }
}

extern "C" void kernel_launch(void* const* d_in, const int* in_sizes, int n_in,
                              void* d_out, int out_size, void* d_ws, size_t ws_size,
                              hipStream_t stream) {
  const float* x   = (const float*)d_in[0];
  const float* w1  = (const float*)d_in[1];
  const float* g1  = (const float*)d_in[2];
  const float* b1  = (const float*)d_in[3];
  const float* m1  = (const float*)d_in[4];
  const float* v1  = (const float*)d_in[5];
  const float* ow  = (const float*)d_in[6];
  const float* ob  = (const float*)d_in[7];
  const float* w2  = (const float*)d_in[8];
  const float* g2  = (const float*)d_in[9];
  const float* b2  = (const float*)d_in[10];
  const float* m2  = (const float*)d_in[11];
  const float* v2  = (const float*)d_in[12];
  float* out  = (float*)d_out;

  float* t1   = (float*)d_ws;                      // NHWC, 25.7 MB
  float* toff = t1 + (size_t)B*CHW;                // 1.8 MB
  float* w2t  = toff + (size_t)B*NOFF*HW;          // 2.36 MB

  prep_w2t<<<(9*256*256 + 255)/256, 256, 0, stream>>>(w2, w2t);

  dim3 grid1(16, 7, 8);
  conv1_bn_relu<<<grid1, 448, 0, stream>>>(x, w1, g1, b1, m1, v1, t1);

  hipMemsetAsync(toff, 0, (size_t)B*NOFF*HW*sizeof(float), stream);
  dim3 grid2(98, 8, 1);
  offset_conv<<<grid2, 256, 0, stream>>>(t1, ow, ob, toff);

  dim3 grid3(8, 7, 8);
  deform_bn_add_relu<<<grid3, 448, 0, stream>>>(t1, w2t, toff, x, g2, b2, m2, v2, out);
}

// Round 3
// 508.658 us; speedup vs baseline: 7.4604x; 5.6090x over previous
//
#include <hip/hip_runtime.h>

#define NB 8
#define NC 256
#define NH 56
#define NW 56
#define NHW 3136          // NH*NW
#define NCHW 802816
#define NPIX 25088        // NB*NHW
#define EPSV 1e-5f

typedef float f32x4 __attribute__((ext_vector_type(4)));
typedef __bf16 bf16x8 __attribute__((ext_vector_type(8)));

__device__ __forceinline__ unsigned short f2b(float f) {
  unsigned int u = __float_as_uint(f);
  u += 0x7FFFu + ((u >> 16) & 1u);
  return (unsigned short)(u >> 16);
}
__device__ __forceinline__ float blo(unsigned int u){ return __uint_as_float(u << 16); }
__device__ __forceinline__ float bhi(unsigned int u){ return __uint_as_float(u & 0xFFFF0000u); }

// ---------------------------------------------------------------------------
// P1: x NCHW fp32 -> xb NHWC bf16.  block: 64 px x 4 ch-groups; grid 392
// ---------------------------------------------------------------------------
__global__ __launch_bounds__(256) void prep_x(
    const float* __restrict__ x, unsigned short* __restrict__ xb)
{
  const int t  = threadIdx.x;
  const int px = blockIdx.x*64 + (t & 63);
  const int cg = (t >> 6) * 64;
  const int b  = px / NHW, rem = px % NHW;
  const float* src = x + (size_t)b*NCHW + rem;
  unsigned short* dst = xb + (size_t)px*256;
  for (int c = cg; c < cg+64; c += 2) {
    float v0 = src[(size_t)c*NHW];
    float v1 = src[(size_t)(c+1)*NHW];
    unsigned int pk = ((unsigned int)f2b(v1) << 16) | (unsigned int)f2b(v0);
    *(unsigned int*)(dst + c) = pk;
  }
}

// ---------------------------------------------------------------------------
// P2: w [256co][256ci][3][3] fp32 -> wp [9k][4cic][256co][64cil] bf16
// ---------------------------------------------------------------------------
__global__ __launch_bounds__(256) void prep_w(
    const float* __restrict__ w, unsigned short* __restrict__ wp)
{
  int i = blockIdx.x*256 + threadIdx.x;    // 9*65536 = 589824 exact
  int cil = i & 63;
  int co  = (i >> 6) & 255;
  int cic = (i >> 14) & 3;
  int k   = i >> 16;
  wp[i] = f2b(w[((size_t)co*256 + cic*64 + cil)*9 + k]);
}

// ---------------------------------------------------------------------------
// GEMM1: conv3x3(xb) + BN + ReLU -> t1b (NHWC bf16)
// M-tile 32 px, N = 256 co, BK = 64; 256 thr = 4 waves; grid NPIX/32 = 784
// ---------------------------------------------------------------------------
__global__ __launch_bounds__(256) void gemm_conv1(
    const unsigned short* __restrict__ xb, const unsigned short* __restrict__ w1p,
    const float* __restrict__ gam, const float* __restrict__ bet,
    const float* __restrict__ mu,  const float* __restrict__ var,
    unsigned short* __restrict__ t1b)
{
  __shared__ unsigned short Al[32*88];
  __shared__ unsigned short Bl[256*88];
  const int m0   = blockIdx.x * 32;
  const int t    = threadIdx.x;
  const int lane = t & 63;
  const int wv   = t >> 6;
  const int quad = lane >> 4;
  const int l15  = lane & 15;

  const int sp  = t & 31;       // sampling pixel within tile
  const int sg  = t >> 5;       // sampling ci-group base (0..7)
  const int px  = m0 + sp;
  const int b   = px / NHW, rem = px % NHW;
  const int ho  = rem / NW, wo = rem % NW;

  f32x4 acc[2][4];
  #pragma unroll
  for (int i = 0; i < 2; ++i)
    #pragma unroll
    for (int j = 0; j < 4; ++j) acc[i][j] = (f32x4)(0.f);

  for (int k = 0; k < 9; ++k) {
    const int ky = k/3, kx = k - ky*3;
    const int iy = ho + ky - 1, ix = wo + kx - 1;
    const bool valid = (iy >= 0) & (iy < NH) & (ix >= 0) & (ix < NW);
    const size_t pbase = ((size_t)(b*NH + iy)*NW + ix)*256;

    for (int cic = 0; cic < 4; ++cic) {
      __syncthreads();
      // stage A: 2 tasks of 4 ci (8B each)
      #pragma unroll
      for (int r = 0; r < 2; ++r) {
        const int g4 = sg + r*8;
        uint2 qv = make_uint2(0u, 0u);
        if (valid) qv = *(const uint2*)(xb + pbase + cic*64 + g4*4);
        *(uint2*)(&Al[sp*88 + g4*4]) = qv;
      }
      // stage B: 256 rows x 64 ci bf16 = 32KB contiguous
      const unsigned short* wsrc = w1p + ((size_t)(k*4 + cic))*(256*64);
      #pragma unroll
      for (int r = 0; r < 8; ++r) {
        int seg = t + r*256;
        int row = seg >> 3, sc = (seg & 7)*8;
        *(uint4*)(&Bl[row*88 + sc]) = *(const uint4*)(wsrc + row*64 + sc);
      }
      __syncthreads();
      #pragma unroll
      for (int kk = 0; kk < 2; ++kk) {
        bf16x8 a0 = *(const bf16x8*)(&Al[(l15     )*88 + kk*32 + quad*8]);
        bf16x8 a1 = *(const bf16x8*)(&Al[(16 + l15)*88 + kk*32 + quad*8]);
        #pragma unroll
        for (int nt = 0; nt < 4; ++nt) {
          int nrow = wv*64 + nt*16 + l15;
          bf16x8 bf = *(const bf16x8*)(&Bl[nrow*88 + kk*32 + quad*8]);
          acc[0][nt] = __builtin_amdgcn_mfma_f32_16x16x32_bf16(a0, bf, acc[0][nt], 0, 0, 0);
          acc[1][nt] = __builtin_amdgcn_mfma_f32_16x16x32_bf16(a1, bf, acc[1][nt], 0, 0, 0);
        }
      }
    }
  }
  // epilogue: BN + ReLU -> bf16 NHWC
  #pragma unroll
  for (int nt = 0; nt < 4; ++nt) {
    int co = wv*64 + nt*16 + l15;
    float inv  = gam[co] * rsqrtf(var[co] + EPSV);
    float beta = bet[co] - mu[co]*inv;
    #pragma unroll
    for (int mt = 0; mt < 2; ++mt) {
      #pragma unroll
      for (int r = 0; r < 4; ++r) {
        int mm = mt*16 + quad*4 + r;
        float val = acc[mt][nt][r]*inv + beta;
        val = val > 0.f ? val : 0.f;
        t1b[(size_t)(m0 + mm)*256 + co] = f2b(val);
      }
    }
  }
}

// ---------------------------------------------------------------------------
// K2: toff += conv3x3(t1b, off_w) (+off_b on chunk 0); toff pre-zeroed
// ---------------------------------------------------------------------------
__global__ __launch_bounds__(256) void offset_conv(
    const unsigned short* __restrict__ t1b, const float* __restrict__ ow,
    const float* __restrict__ ob, float* __restrict__ toff)
{
  const int p = blockIdx.x*256 + threadIdx.x;    // 98*256 = 25088
  const int cichunk = blockIdx.y * 32;
  const int b  = p / NHW, rem = p % NHW;
  const int ho = rem / NW, wo = rem % NW;

  float acc[18];
  if (blockIdx.y == 0) {
    #pragma unroll
    for (int c = 0; c < 18; ++c) acc[c] = ob[c];
  } else {
    #pragma unroll
    for (int c = 0; c < 18; ++c) acc[c] = 0.f;
  }

  #pragma unroll
  for (int ky = 0; ky < 3; ++ky) {
    int y = ho - 1 + ky;
    if (y < 0 || y >= NH) continue;
    #pragma unroll
    for (int kx = 0; kx < 3; ++kx) {
      int xx = wo - 1 + kx;
      if (xx < 0 || xx >= NW) continue;
      const int k = ky*3 + kx;
      const unsigned short* base = t1b + ((size_t)(b*NH + y)*NW + xx)*256 + cichunk;
      for (int q = 0; q < 8; ++q) {
        uint2 u = *(const uint2*)(base + q*4);
        float f0 = blo(u.x), f1 = bhi(u.x), f2v = blo(u.y), f3 = bhi(u.y);
        const int ci = cichunk + q*4;
        #pragma unroll
        for (int c = 0; c < 18; ++c) {
          const float* wr = ow + ((size_t)c*256 + ci)*9 + k;   // uniform -> s_load
          acc[c] += f0*wr[0] + f1*wr[9] + f2v*wr[18] + f3*wr[27];
        }
      }
    }
  }
  float* od = toff + (size_t)b*(18*NHW) + rem;
  #pragma unroll
  for (int c = 0; c < 18; ++c)
    atomicAdd(od + c*NHW, acc[c]);
}

// ---------------------------------------------------------------------------
// GEMM2: deform_conv(t1b, w2, toff) + BN + residual + ReLU -> out (NCHW fp32)
// ---------------------------------------------------------------------------
__global__ __launch_bounds__(256) void gemm_deform(
    const unsigned short* __restrict__ t1b, const unsigned short* __restrict__ w2p,
    const float* __restrict__ toff, const float* __restrict__ xres,
    const float* __restrict__ gam, const float* __restrict__ bet,
    const float* __restrict__ mu,  const float* __restrict__ var,
    float* __restrict__ outp)
{
  __shared__ unsigned short Al[32*88];
  __shared__ unsigned short Bl[256*88];
  const int m0   = blockIdx.x * 32;
  const int t    = threadIdx.x;
  const int lane = t & 63;
  const int wv   = t >> 6;
  const int quad = lane >> 4;
  const int l15  = lane & 15;

  const int sp  = t & 31;
  const int sg  = t >> 5;
  const int px  = m0 + sp;
  const int b   = px / NHW, rem = px % NHW;
  const int ho  = rem / NW, wo = rem % NW;

  f32x4 acc[2][4];
  #pragma unroll
  for (int i = 0; i < 2; ++i)
    #pragma unroll
    for (int j = 0; j < 4; ++j) acc[i][j] = (f32x4)(0.f);

  for (int k = 0; k < 9; ++k) {
    const int ky = k/3, kx = k - ky*3;
    // per-pixel corner bases + bilinear weights (shared across all ci)
    float offy = toff[(size_t)b*(18*NHW) + k*NHW + rem];
    float offx = toff[(size_t)b*(18*NHW) + (9+k)*NHW + rem];
    float yf = (float)(ho - 1 + ky) + offy;
    float xf = (float)(wo - 1 + kx) + offx;
    float y0f = floorf(yf), x0f = floorf(xf);
    float ty = yf - y0f,   tx = xf - x0f;
    int y0 = (int)y0f, x0 = (int)x0f;
    int y1 = y0 + 1,   x1 = x0 + 1;
    bool vy0 = (y0 >= 0) & (y0 < NH);
    bool vy1 = (y1 >= 0) & (y1 < NH);
    bool vx0 = (x0 >= 0) & (x0 < NW);
    bool vx1 = (x1 >= 0) & (x1 < NW);
    int cy0 = min(max(y0,0),NH-1), cy1 = min(max(y1,0),NH-1);
    int cx0 = min(max(x0,0),NW-1), cx1 = min(max(x1,0),NW-1);
    float wy0 = 1.f - ty, wx0 = 1.f - tx;
    float w00 = (vy0 & vx0) ? wy0*wx0 : 0.f;
    float w01 = (vy0 & vx1) ? wy0*tx  : 0.f;
    float w10 = (vy1 & vx0) ? ty*wx0  : 0.f;
    float w11 = (vy1 & vx1) ? ty*tx   : 0.f;
    const unsigned int rb = (unsigned int)(b*NH);
    unsigned int o00 = ((rb + cy0)*NW + cx0)*256u;
    unsigned int o01 = ((rb + cy0)*NW + cx1)*256u;
    unsigned int o10 = ((rb + cy1)*NW + cx0)*256u;
    unsigned int o11 = ((rb + cy1)*NW + cx1)*256u;

    for (int cic = 0; cic < 4; ++cic) {
      __syncthreads();
      #pragma unroll
      for (int r = 0; r < 2; ++r) {
        const int g4 = sg + r*8;
        const unsigned int cio = cic*64 + g4*4;
        uint2 q00 = *(const uint2*)(t1b + o00 + cio);
        uint2 q01 = *(const uint2*)(t1b + o01 + cio);
        uint2 q10 = *(const uint2*)(t1b + o10 + cio);
        uint2 q11 = *(const uint2*)(t1b + o11 + cio);
        float v0 = w00*blo(q00.x) + w01*blo(q01.x) + w10*blo(q10.x) + w11*blo(q11.x);
        float v1 = w00*bhi(q00.x) + w01*bhi(q01.x) + w10*bhi(q10.x) + w11*bhi(q11.x);
        float v2 = w00*blo(q00.y) + w01*blo(q01.y) + w10*blo(q10.y) + w11*blo(q11.y);
        float v3 = w00*bhi(q00.y) + w01*bhi(q01.y) + w10*bhi(q10.y) + w11*bhi(q11.y);
        uint2 o;
        o.x = ((unsigned int)f2b(v1) << 16) | (unsigned int)f2b(v0);
        o.y = ((unsigned int)f2b(v3) << 16) | (unsigned int)f2b(v2);
        *(uint2*)(&Al[sp*88 + g4*4]) = o;
      }
      const unsigned short* wsrc = w2p + ((size_t)(k*4 + cic))*(256*64);
      #pragma unroll
      for (int r = 0; r < 8; ++r) {
        int seg = t + r*256;
        int row = seg >> 3, sc = (seg & 7)*8;
        *(uint4*)(&Bl[row*88 + sc]) = *(const uint4*)(wsrc + row*64 + sc);
      }
      __syncthreads();
      #pragma unroll
      for (int kk = 0; kk < 2; ++kk) {
        bf16x8 a0 = *(const bf16x8*)(&Al[(l15     )*88 + kk*32 + quad*8]);
        bf16x8 a1 = *(const bf16x8*)(&Al[(16 + l15)*88 + kk*32 + quad*8]);
        #pragma unroll
        for (int nt = 0; nt < 4; ++nt) {
          int nrow = wv*64 + nt*16 + l15;
          bf16x8 bf = *(const bf16x8*)(&Bl[nrow*88 + kk*32 + quad*8]);
          acc[0][nt] = __builtin_amdgcn_mfma_f32_16x16x32_bf16(a0, bf, acc[0][nt], 0, 0, 0);
          acc[1][nt] = __builtin_amdgcn_mfma_f32_16x16x32_bf16(a1, bf, acc[1][nt], 0, 0, 0);
        }
      }
    }
  }
  // epilogue: BN + residual + ReLU -> fp32 NCHW, float4 stores
  #pragma unroll
  for (int mt = 0; mt < 2; ++mt) {
    int p4 = m0 + mt*16 + quad*4;
    int b2 = p4 / NHW, rem2 = p4 % NHW;
    #pragma unroll
    for (int nt = 0; nt < 4; ++nt) {
      int co = wv*64 + nt*16 + l15;
      float inv  = gam[co] * rsqrtf(var[co] + EPSV);
      float beta = bet[co] - mu[co]*inv;
      size_t off = (size_t)b2*NCHW + (size_t)co*NHW + rem2;
      float4 res = *(const float4*)(xres + off);
      float4 o;
      o.x = acc[mt][nt][0]*inv + beta + res.x;
      o.y = acc[mt][nt][1]*inv + beta + res.y;
      o.z = acc[mt][nt][2]*inv + beta + res.z;
      o.w = acc[mt][nt][3]*inv + beta + res.w;
      o.x = o.x > 0.f ? o.x : 0.f;
      o.y = o.y > 0.f ? o.y : 0.f;
      o.z = o.z > 0.f ? o.z : 0.f;
      o.w = o.w > 0.f ? o.w : 0.f;
      *(float4*)(outp + off) = o;
    }
  }
}

extern "C" void kernel_launch(void* const* d_in, const int* in_sizes, int n_in,
                              void* d_out, int out_size, void* d_ws, size_t ws_size,
                              hipStream_t stream) {
  const float* x   = (const float*)d_in[0];
  const float* w1  = (const float*)d_in[1];
  const float* g1  = (const float*)d_in[2];
  const float* b1  = (const float*)d_in[3];
  const float* m1  = (const float*)d_in[4];
  const float* v1  = (const float*)d_in[5];
  const float* ow  = (const float*)d_in[6];
  const float* ob  = (const float*)d_in[7];
  const float* w2  = (const float*)d_in[8];
  const float* g2  = (const float*)d_in[9];
  const float* b2  = (const float*)d_in[10];
  const float* m2  = (const float*)d_in[11];
  const float* v2  = (const float*)d_in[12];
  float* out = (float*)d_out;

  // workspace layout (bytes): xb 12.85M | t1b 12.85M | toff 1.81M | w1p 1.18M | w2p 1.18M
  unsigned short* xb  = (unsigned short*)d_ws;
  unsigned short* t1b = xb + (size_t)NPIX*256;
  float*          tof = (float*)(t1b + (size_t)NPIX*256);
  unsigned short* w1p = (unsigned short*)(tof + (size_t)NB*18*NHW);
  unsigned short* w2p = w1p + (size_t)589824;

  prep_x<<<392, 256, 0, stream>>>(x, xb);
  prep_w<<<2304, 256, 0, stream>>>(w1, w1p);
  prep_w<<<2304, 256, 0, stream>>>(w2, w2p);

  gemm_conv1<<<784, 256, 0, stream>>>(xb, w1p, g1, b1, m1, v1, t1b);

  hipMemsetAsync(tof, 0, (size_t)NB*18*NHW*sizeof(float), stream);
  dim3 grid2(98, 8, 1);
  offset_conv<<<grid2, 256, 0, stream>>>(t1b, ow, ob, tof);

  gemm_deform<<<784, 256, 0, stream>>>(t1b, w2p, tof, x, g2, b2, m2, v2, out);
}